// Round 12
// baseline (105.794 us; speedup 1.0000x reference)
//
#include <hip/hip_runtime.h>
#include <hip/hip_bf16.h>

typedef float  f32x16 __attribute__((ext_vector_type(16)));
typedef short  bf16x8 __attribute__((ext_vector_type(8)));

__device__ __forceinline__ unsigned short f2bf(float x) {  // RNE, for weights/T/v
  union { float f; unsigned u; } v; v.f = x;
  return (unsigned short)((v.u + 0x7FFFu + ((v.u >> 16) & 1u)) >> 16);
}
__device__ __forceinline__ float bf2f(unsigned short u) {
  union { unsigned u; float f; } v; v.u = ((unsigned)u) << 16; return v.f;
}
__device__ __forceinline__ float celu1(float x) {
  return x > 0.f ? x : (__expf(x) - 1.f);
}

__device__ __forceinline__ bf16x8 to_frag(float4 a, float4 b) {  // RNE path
  bf16x8 r;
  r[0] = (short)f2bf(a.x); r[1] = (short)f2bf(a.y);
  r[2] = (short)f2bf(a.z); r[3] = (short)f2bf(a.w);
  r[4] = (short)f2bf(b.x); r[5] = (short)f2bf(b.y);
  r[6] = (short)f2bf(b.z); r[7] = (short)f2bf(b.w);
  return r;
}

// fast pack: two f32 -> {lo:bf16(a), hi:bf16(b)} with +0x8000 round-half (1 perm + 2 adds)
__device__ __forceinline__ unsigned pack_rh(unsigned ua, unsigned ub) {
  return __builtin_amdgcn_perm(ub + 0x8000u, ua + 0x8000u, 0x07060302u);
}
__device__ __forceinline__ bf16x8 to_frag_rh(float4 a, float4 b) {
  union { float4 f; unsigned u[4]; } A, B; A.f = a; B.f = b;
  union { unsigned u[4]; bf16x8 v; } r;
  r.u[0] = pack_rh(A.u[0], A.u[1]);
  r.u[1] = pack_rh(A.u[2], A.u[3]);
  r.u[2] = pack_rh(B.u[0], B.u[1]);
  r.u[3] = pack_rh(B.u[2], B.u[3]);
  return r.v;
}

// LDS W^T image, bf16, XOR-swizzled in 8-elem (16B) slots
__device__ __forceinline__ bf16x8 ldsfrag(const unsigned short* w, int S, int col, int k0) {
  return *reinterpret_cast<const bf16x8*>(w + col * S + (k0 ^ ((col & 7) << 3)));
}

// B-fragment gathered from row-major global W[k][col]; L2-hot.
__device__ __forceinline__ bf16x8 wfrag(const float* __restrict__ W, int ld, int col, int k0) {
  bf16x8 f;
#pragma unroll
  for (int j = 0; j < 8; ++j) f[j] = (short)f2bf(W[(size_t)(k0 + j) * ld + col]);
  return f;
}

struct Stage { float4 a[4][2]; };  // one node's 32x64 f32 nbr tile slice per lane

__global__ __launch_bounds__(256, 3) void gcu_kernel(
    const float* __restrict__ z, const float* __restrict__ z_,
    const float* __restrict__ Wc, const float* __restrict__ bc,
    const float* __restrict__ Wn, const float* __restrict__ bn,
    const float* __restrict__ Wo, const float* __restrict__ bo,
    float* __restrict__ out, int N) {
  __shared__ __align__(16) unsigned short sWnT[64 * 128];   // 16 KB, block-shared
  __shared__ __align__(16) unsigned short sT[4][32 * 64];   // 16 KB: T, then reused as v
  __shared__ __align__(16) unsigned short sV[4][32 * 64];   // 16 KB: v_ image
  // total 48 KB/block -> 3 blocks/CU (12 waves)

  const int tid = threadIdx.x;
  const int wid = tid >> 6, lane = tid & 63;
  const int lo = lane & 31, hi = lane >> 5;

  // ---- stage W_nbr^T (bf16, swizzled) into LDS ----
  for (int i = tid; i < 128 * 64; i += 256) {
    int c = i & 63, k = i >> 6;
    sWnT[c * 128 + (k ^ ((c & 7) << 3))] = f2bf(Wn[i]);
  }
  __syncthreads();  // single block barrier

  // node-interleaved mapping: wave g owns nodes {g + j*NW} -> moving ~24 MB window
  const int gw = blockIdx.x * 4 + wid;
  const int NW = (int)gridDim.x * 4;              // 3072
  const int cnt = (N - gw + NW - 1) / NW;         // 16 or 17
  if (cnt <= 0) return;

  unsigned short* tt = &sT[wid][0];
  unsigned short* sv = &sV[wid][0];

  auto nodep = [&](int j) { return z_ + (size_t)min(gw + j * NW, N - 1) * 2048; };
  auto issue_stage = [&](Stage& s, const float* p) {
#pragma unroll
    for (int ks = 0; ks < 4; ++ks) {
      const float* pa = p + lo * 64 + ks * 16 + 8 * hi;
      s.a[ks][0] = *reinterpret_cast<const float4*>(pa);
      s.a[ks][1] = *reinterpret_cast<const float4*>(pa + 4);
    }
  };

  const float bn0 = bn[lo], bn1 = bn[32 + lo];
  const float bc0 = bc[lo], bc1 = bc[32 + lo];
  const float bo0 = bo[lo], bo1 = bo[32 + lo];

  // ---- z-fragments (tile row j <-> node gw + j*NW, clamped) ----
  bf16x8 zf[4];
  {
    int node = min(gw + lo * NW, N - 1);
    const float* zp = z + (size_t)node * 64;
#pragma unroll
    for (int ks = 0; ks < 4; ++ks) {
      float4 x0 = *reinterpret_cast<const float4*>(zp + ks * 16 + 8 * hi);
      float4 x1 = *reinterpret_cast<const float4*>(zp + ks * 16 + 8 * hi + 4);
      zf[ks] = to_frag(x0, x1);
    }
  }

  Stage sA, sB;
  issue_stage(sA, nodep(0));
  issue_stage(sB, nodep(1));

  // ---- T = Z_tile @ Wn_top (self-half of concat GEMM; overlaps prologue loads) ----
  {
    f32x16 a0{}, a1{};
#pragma unroll
    for (int ks = 0; ks < 4; ++ks) {
      int k0 = ks * 16 + 8 * hi;
      bf16x8 b0 = ldsfrag(sWnT, 128, lo, k0);
      bf16x8 b1 = ldsfrag(sWnT, 128, lo + 32, k0);
      a0 = __builtin_amdgcn_mfma_f32_32x32x16_bf16(zf[ks], b0, a0, 0, 0, 0);
      a1 = __builtin_amdgcn_mfma_f32_32x32x16_bf16(zf[ks], b1, a1, 0, 0, 0);
    }
#pragma unroll
    for (int r = 0; r < 16; ++r) {
      int row = (r & 3) + 8 * (r >> 2) + 4 * hi;
      tt[row * 64 + lo]      = f2bf(a0[r]);
      tt[row * 64 + 32 + lo] = f2bf(a1[r]);
    }
  }

  // per node: convert -> refill -> MFMA (B from LDS, no hoist: saves 32 VGPR) -> celu-colsum
  auto process = [&](Stage& s, int nn, const float* refill) {
    bf16x8 af[4];
#pragma unroll
    for (int ks = 0; ks < 4; ++ks) af[ks] = to_frag_rh(s.a[ks][0], s.a[ks][1]);
    issue_stage(s, refill);   // refill right after conversion; hides under MFMA+celu
    f32x16 acc0{}, acc1{};
#pragma unroll
    for (int ks = 0; ks < 4; ++ks) {
      int k0 = 64 + ks * 16 + 8 * hi;
      acc0 = __builtin_amdgcn_mfma_f32_32x32x16_bf16(af[ks], ldsfrag(sWnT, 128, lo, k0),      acc0, 0, 0, 0);
      acc1 = __builtin_amdgcn_mfma_f32_32x32x16_bf16(af[ks], ldsfrag(sWnT, 128, lo + 32, k0), acc1, 0, 0, 0);
    }
    float c0 = bn0 + bf2f(tt[nn * 64 + lo]);
    float c1 = bn1 + bf2f(tt[nn * 64 + 32 + lo]);
    float s0 = 0.f, s1 = 0.f;
#pragma unroll
    for (int r = 0; r < 16; ++r) {
      s0 += celu1(acc0[r] + c0);
      s1 += celu1(acc1[r] + c1);
    }
    s0 += __shfl_xor(s0, 32, 64);
    s1 += __shfl_xor(s1, 32, 64);
    if (hi == 0) {
      int m = (nn & 7) << 3;
      sv[nn * 64 + ( lo       ^ m)] = f2bf(s0);
      sv[nn * 64 + ((32 + lo) ^ m)] = f2bf(s1);
    }
  };

  const int pairs = cnt >> 1, odd = cnt & 1;
#pragma unroll 1
  for (int i = 0; i < pairs; ++i) {
    process(sA, 2 * i,     nodep(2 * i + 2));   // clamped prefetch beyond end is L2-cheap
    process(sB, 2 * i + 1, nodep(2 * i + 3));
  }
  if (odd) process(sA, cnt - 1, nodep(cnt - 1));

  // ---- cur branch: v = celu(z @ W_cur + b_cur) -> reuse tt buffer as v image ----
  unsigned short* vt = tt;  // T fully consumed by the node loop
  {
    f32x16 a0{}, a1{};
#pragma unroll
    for (int ks = 0; ks < 4; ++ks) {
      int k0 = ks * 16 + 8 * hi;
      a0 = __builtin_amdgcn_mfma_f32_32x32x16_bf16(zf[ks], wfrag(Wc, 64, lo, k0), a0, 0, 0, 0);
      a1 = __builtin_amdgcn_mfma_f32_32x32x16_bf16(zf[ks], wfrag(Wc, 64, lo + 32, k0), a1, 0, 0, 0);
    }
#pragma unroll
    for (int r = 0; r < 16; ++r) {
      int row = (r & 3) + 8 * (r >> 2) + 4 * hi;
      int m = (row & 7) << 3;
      vt[row * 64 + ( lo       ^ m)] = f2bf(celu1(a0[r] + bc0));
      vt[row * 64 + ((32 + lo) ^ m)] = f2bf(celu1(a1[r] + bc1));
    }
  }

  // ---- out: dc = (v || v_) @ W_out + b_out ----
  {
    f32x16 a0{}, a1{};
    const int mm = (lo & 7) << 3;
#pragma unroll
    for (int ks = 0; ks < 8; ++ks) {
      int k0 = ks * 16 + 8 * hi;
      bf16x8 af;
      if (ks < 4) af = *reinterpret_cast<const bf16x8*>(vt + lo * 64 + ( k0       ^ mm));
      else        af = *reinterpret_cast<const bf16x8*>(sv + lo * 64 + ((k0 - 64) ^ mm));
      a0 = __builtin_amdgcn_mfma_f32_32x32x16_bf16(af, wfrag(Wo, 64, lo, k0), a0, 0, 0, 0);
      a1 = __builtin_amdgcn_mfma_f32_32x32x16_bf16(af, wfrag(Wo, 64, lo + 32, k0), a1, 0, 0, 0);
    }
#pragma unroll
    for (int r = 0; r < 16; ++r) {
      int rr = (r & 3) + 8 * (r >> 2) + 4 * hi;   // local tile row
      int row = gw + rr * NW;                      // global node
      if (row < N) {
        out[(size_t)row * 64 + lo]      = a0[r] + bo0;
        out[(size_t)row * 64 + 32 + lo] = a1[r] + bo1;
      }
    }
  }
}

extern "C" void kernel_launch(void* const* d_in, const int* in_sizes, int n_in,
                              void* d_out, int out_size, void* d_ws, size_t ws_size,
                              hipStream_t stream) {
  const float* z  = (const float*)d_in[0];
  const float* z_ = (const float*)d_in[1];
  const float* Wc = (const float*)d_in[2];
  const float* bc = (const float*)d_in[3];
  const float* Wn = (const float*)d_in[4];
  const float* bn = (const float*)d_in[5];
  const float* Wo = (const float*)d_in[6];
  const float* bo = (const float*)d_in[7];
  float* out = (float*)d_out;
  const int N = in_sizes[0] / 64;  // 50000
  // 768 blocks = 3 blocks/CU (48 KB LDS each), 3072 waves, node-interleaved tasks
  gcu_kernel<<<768, 256, 0, stream>>>(z, z_, Wc, bc, Wn, bn, Wo, bo, out, N);
}

// Round 13
// 87.435 us; speedup vs baseline: 1.2100x; 1.2100x over previous
//
#include <hip/hip_runtime.h>
#include <hip/hip_bf16.h>

typedef float  f32x16 __attribute__((ext_vector_type(16)));
typedef short  bf16x8 __attribute__((ext_vector_type(8)));

__device__ __forceinline__ unsigned short f2bf(float x) {
  union { float f; unsigned u; } v; v.f = x;
  return (unsigned short)((v.u + 0x7FFFu + ((v.u >> 16) & 1u)) >> 16);
}
__device__ __forceinline__ float bf2f(unsigned short u) {
  union { unsigned u; float f; } v; v.u = ((unsigned)u) << 16; return v.f;
}
__device__ __forceinline__ float celu1(float x) {
  return x > 0.f ? x : (__expf(x) - 1.f);
}

__device__ __forceinline__ bf16x8 to_frag(float4 a, float4 b) {
  bf16x8 r;
  r[0] = (short)f2bf(a.x); r[1] = (short)f2bf(a.y);
  r[2] = (short)f2bf(a.z); r[3] = (short)f2bf(a.w);
  r[4] = (short)f2bf(b.x); r[5] = (short)f2bf(b.y);
  r[6] = (short)f2bf(b.z); r[7] = (short)f2bf(b.w);
  return r;
}

// LDS W^T image, bf16, XOR-swizzled in 8-elem (16B) slots: elem = k ^ ((col&7)<<3)
__device__ __forceinline__ bf16x8 ldsfrag(const unsigned short* w, int S, int col, int k0) {
  return *reinterpret_cast<const bf16x8*>(w + col * S + (k0 ^ ((col & 7) << 3)));
}

// B-fragment gathered from row-major global W[k][col]; L2-hot.
__device__ __forceinline__ bf16x8 wfrag(const float* __restrict__ W, int ld, int col, int k0) {
  bf16x8 f;
#pragma unroll
  for (int j = 0; j < 8; ++j) f[j] = (short)f2bf(W[(size_t)(k0 + j) * ld + col]);
  return f;
}

__global__ __launch_bounds__(256, 2) void gcu_kernel(
    const float* __restrict__ z, const float* __restrict__ z_,
    const float* __restrict__ Wc, const float* __restrict__ bc,
    const float* __restrict__ Wn, const float* __restrict__ bn,
    const float* __restrict__ Wo, const float* __restrict__ bo,
    float* __restrict__ out, int N) {
  __shared__ __align__(16) unsigned short sWnT[64 * 128];   // 16 KB, block-shared
  __shared__ __align__(16) unsigned short sT[4][32 * 64];   // 16 KB, self-half partials
  __shared__ __align__(16) unsigned short sV[4][32 * 64];   // 16 KB, v_ image
  __shared__ __align__(16) float sTile[4][32 * 64];         // 32 KB, DMA tile / v image

  const int tid = threadIdx.x;
  const int wid = tid >> 6, lane = tid & 63;
  const int lo = lane & 31, hi = lane >> 5;

  // ---- stage W_nbr^T (bf16, swizzled) into LDS ----
  for (int i = tid; i < 128 * 64; i += 256) {
    int c = i & 63, k = i >> 6;
    sWnT[c * 128 + (k ^ ((c & 7) << 3))] = f2bf(Wn[i]);
  }
  __syncthreads();  // single block barrier

  // node-interleaved mapping: wave g owns nodes {g + j*NW}. At any instant the
  // 2048 waves' current tiles form a contiguous ~16-32 MB moving window of z_
  // (DRAM-sequential per channel, L3-resident) instead of 2048 scattered streams.
  const int gw = blockIdx.x * 4 + wid;
  const int NW = (int)gridDim.x * 4;              // 2048
  const int cnt = (N - gw + NW - 1) / NW;         // 24 or 25
  if (cnt <= 0) return;

  unsigned short* tt = &sT[wid][0];
  unsigned short* sv = &sV[wid][0];
  float* tile = &sTile[wid][0];

  // DMA: per-lane pre-swizzled source offsets; LDS written linearly
  const int rl = lane >> 4, tl = lane & 15;
  const int o0 = rl * 64 + ((tl ^ rl) << 2);
  const int o1 = o0 ^ 16;
  auto stage_tile = [&](const float* gb) {
#pragma unroll
    for (int i = 0; i < 8; ++i) {
      const float* src = gb + i * 256 + ((i & 1) ? o1 : o0);
      __builtin_amdgcn_global_load_lds(
          (const __attribute__((address_space(1))) unsigned*)src,
          (__attribute__((address_space(3))) unsigned*)(tile + i * 256),
          16, 0, 0);
    }
  };

  stage_tile(z_ + (size_t)gw * 2048);  // prefetch node j=0

  const float bn0 = bn[lo], bn1 = bn[32 + lo];
  const float bc0 = bc[lo], bc1 = bc[32 + lo];
  const float bo0 = bo[lo], bo1 = bo[32 + lo];

  // ---- z-fragments: tile row j <-> node gw + j*NW (clamped; rows >= cnt masked later)
  bf16x8 zf[4];
  {
    int node = min(gw + lo * NW, N - 1);
    const float* zp = z + (size_t)node * 64;
#pragma unroll
    for (int ks = 0; ks < 4; ++ks) {
      float4 x0 = *reinterpret_cast<const float4*>(zp + ks * 16 + 8 * hi);
      float4 x1 = *reinterpret_cast<const float4*>(zp + ks * 16 + 8 * hi + 4);
      zf[ks] = to_frag(x0, x1);
    }
  }

  // ---- T = Z_tile @ Wn_top (self-half of concat GEMM, once per task) ----
  {
    f32x16 a0{}, a1{};
#pragma unroll
    for (int ks = 0; ks < 4; ++ks) {
      int k0 = ks * 16 + 8 * hi;
      bf16x8 b0 = ldsfrag(sWnT, 128, lo, k0);
      bf16x8 b1 = ldsfrag(sWnT, 128, lo + 32, k0);
      a0 = __builtin_amdgcn_mfma_f32_32x32x16_bf16(zf[ks], b0, a0, 0, 0, 0);
      a1 = __builtin_amdgcn_mfma_f32_32x32x16_bf16(zf[ks], b1, a1, 0, 0, 0);
    }
#pragma unroll
    for (int r = 0; r < 16; ++r) {
      int row = (r & 3) + 8 * (r >> 2) + 4 * hi;
      tt[row * 64 + lo]      = f2bf(a0[r]);
      tt[row * 64 + 32 + lo] = f2bf(a1[r]);
    }
  }

  // ---- hoist Wn_bot^T B-fragments into VGPRs ----
  bf16x8 Bn_[4][2];
#pragma unroll
  for (int ks = 0; ks < 4; ++ks) {
    int k0 = 64 + ks * 16 + 8 * hi;
    Bn_[ks][0] = ldsfrag(sWnT, 128, lo, k0);
    Bn_[ks][1] = ldsfrag(sWnT, 128, lo + 32, k0);
  }

  // task-invariant swizzled ds_read offsets (bytes)
  int roff[8];
#pragma unroll
  for (int ks = 0; ks < 4; ++ks)
#pragma unroll
    for (int p = 0; p < 2; ++p)
      roff[ks * 2 + p] = lo * 256 + (((ks * 4 + 2 * hi + p) ^ (lo & 7)) << 4);
  const char* tb = (const char*)tile;

#pragma unroll 1
  for (int nn = 0; nn < cnt; ++nn) {
    asm volatile("s_waitcnt vmcnt(0)" ::: "memory");   // tile nn landed in LDS
    __builtin_amdgcn_sched_barrier(0);
    float4 q[8];
#pragma unroll
    for (int j = 0; j < 8; ++j) q[j] = *reinterpret_cast<const float4*>(tb + roff[j]);
    bf16x8 af[4];
#pragma unroll
    for (int ks = 0; ks < 4; ++ks) af[ks] = to_frag(q[2 * ks], q[2 * ks + 1]);
    asm volatile("s_waitcnt lgkmcnt(0)" ::: "memory"); // reads done -> safe overwrite
    __builtin_amdgcn_sched_barrier(0);
    if (nn + 1 < cnt) stage_tile(z_ + (size_t)(gw + (nn + 1) * NW) * 2048);

    float c0 = bn0 + bf2f(tt[nn * 64 + lo]);
    float c1 = bn1 + bf2f(tt[nn * 64 + 32 + lo]);
    f32x16 acc0{}, acc1{};
#pragma unroll
    for (int ks = 0; ks < 4; ++ks) {
      acc0 = __builtin_amdgcn_mfma_f32_32x32x16_bf16(af[ks], Bn_[ks][0], acc0, 0, 0, 0);
      acc1 = __builtin_amdgcn_mfma_f32_32x32x16_bf16(af[ks], Bn_[ks][1], acc1, 0, 0, 0);
    }
    float s0 = 0.f, s1 = 0.f;
#pragma unroll
    for (int r = 0; r < 16; ++r) {
      s0 += celu1(acc0[r] + c0);
      s1 += celu1(acc1[r] + c1);
    }
    s0 += __shfl_xor(s0, 32, 64);
    s1 += __shfl_xor(s1, 32, 64);
    if (hi == 0) {
      int m = (nn & 7) << 3;
      sv[nn * 64 + ( lo       ^ m)] = f2bf(s0);
      sv[nn * 64 + ((32 + lo) ^ m)] = f2bf(s1);
    }
  }

  // ---- cur branch: v = celu(z @ W_cur + b_cur) -> v image in (dead) tile buffer ----
  unsigned short* vt = (unsigned short*)tile;
  asm volatile("s_waitcnt vmcnt(0)" ::: "memory");  // last DMA drained before overwrite
  {
    f32x16 a0{}, a1{};
#pragma unroll
    for (int ks = 0; ks < 4; ++ks) {
      int k0 = ks * 16 + 8 * hi;
      a0 = __builtin_amdgcn_mfma_f32_32x32x16_bf16(zf[ks], wfrag(Wc, 64, lo, k0), a0, 0, 0, 0);
      a1 = __builtin_amdgcn_mfma_f32_32x32x16_bf16(zf[ks], wfrag(Wc, 64, lo + 32, k0), a1, 0, 0, 0);
    }
#pragma unroll
    for (int r = 0; r < 16; ++r) {
      int row = (r & 3) + 8 * (r >> 2) + 4 * hi;
      int m = (row & 7) << 3;
      vt[row * 64 + ( lo       ^ m)] = f2bf(celu1(a0[r] + bc0));
      vt[row * 64 + ((32 + lo) ^ m)] = f2bf(celu1(a1[r] + bc1));
    }
  }

  // ---- out: dc = (v || v_) @ W_out + b_out ----
  {
    f32x16 a0{}, a1{};
    const int mm = (lo & 7) << 3;
#pragma unroll
    for (int ks = 0; ks < 8; ++ks) {
      int k0 = ks * 16 + 8 * hi;
      bf16x8 af;
      if (ks < 4) af = *reinterpret_cast<const bf16x8*>(vt + lo * 64 + ( k0       ^ mm));
      else        af = *reinterpret_cast<const bf16x8*>(sv + lo * 64 + ((k0 - 64) ^ mm));
      a0 = __builtin_amdgcn_mfma_f32_32x32x16_bf16(af, wfrag(Wo, 64, lo, k0), a0, 0, 0, 0);
      a1 = __builtin_amdgcn_mfma_f32_32x32x16_bf16(af, wfrag(Wo, 64, lo + 32, k0), a1, 0, 0, 0);
    }
#pragma unroll
    for (int r = 0; r < 16; ++r) {
      int rr = (r & 3) + 8 * (r >> 2) + 4 * hi;     // local tile row
      int row = gw + rr * NW;                        // global node
      if (row < N) {
        out[(size_t)row * 64 + lo]      = a0[r] + bo0;
        out[(size_t)row * 64 + 32 + lo] = a1[r] + bo1;
      }
    }
  }
}

extern "C" void kernel_launch(void* const* d_in, const int* in_sizes, int n_in,
                              void* d_out, int out_size, void* d_ws, size_t ws_size,
                              hipStream_t stream) {
  const float* z  = (const float*)d_in[0];
  const float* z_ = (const float*)d_in[1];
  const float* Wc = (const float*)d_in[2];
  const float* bc = (const float*)d_in[3];
  const float* Wn = (const float*)d_in[4];
  const float* bn = (const float*)d_in[5];
  const float* Wo = (const float*)d_in[6];
  const float* bo = (const float*)d_in[7];
  float* out = (float*)d_out;
  const int N = in_sizes[0] / 64;  // 50000
  gcu_kernel<<<512, 256, 0, stream>>>(z, z_, Wc, bc, Wn, bn, Wo, bo, out, N);
}